// Round 6
// baseline (474.689 us; speedup 1.0000x reference)
//
#include <hip/hip_runtime.h>
#include <hip/hip_fp16.h>

#define GDIM 96
#define GCELLS (GDIM * GDIM * GDIM)
#define TILE 8
#define HALO 12            // TILE + 2*2
#define NT (GDIM / TILE)   // 12 tiles per axis -> 1728 blocks
#define HCELLS (HALO * HALO * HALO)   // 1728
#define TCELLS (TILE * TILE * TILE)   // 512
#define EMPTY16 0xFBFBu
#define EMPTY32 0xFBFBFBFBu

// grid record (16 B/cell): { jx|jy<<16, jz|vx<<16, vy|vz<<16, pid+1 }
// jitter in CELL units relative to own cell center, f16. Empty cells hold the
// 0xFB memset pattern: jitter approx -6.5e4 cells -> never within contact range.
// At LDS-staging, the periodic wrap delta (0/+96/-96 cells) is folded into the
// staged jitter so wrapped neighbors sit at their true unwrapped relative
// distance (~94 cells -> no contact), matching the reference's physics.

// per-(iz,iy) x-width of offsets where a REAL neighbor can produce contact
// (dist < 2 cells given per-axis jitter <= 0.30013 cells incl. f16 rounding);
// pruned offsets have min dist >= 2.019 cells. 93 of 125 survive.
constexpr int WT_[25] = {1,3,5,3,1, 3,5,5,5,3, 5,5,5,5,5, 3,5,5,5,3, 1,3,5,3,1};

__device__ inline float2 h2f(unsigned int u) {
    union { unsigned int u; __half2 h; } c; c.u = u;
    return __half22float2(c.h);
}
__device__ inline unsigned int f2h(float a, float b) {
    union { __half2 h; unsigned int u; } c; c.h = __floats2half2_rn(a, b);
    return c.u;
}

__global__ __launch_bounds__(256) void scatter_k(
    const float* __restrict__ x, const float* __restrict__ y, const float* __restrict__ z,
    const float* __restrict__ vx, const float* __restrict__ vy, const float* __restrict__ vz,
    const float* __restrict__ dp, const float* __restrict__ knp,
    uint4* __restrict__ grid, float* __restrict__ out, int n)
{
    int i = blockIdx.x * blockDim.x + threadIdx.x;
    if (i >= n) return;
    float d = dp[0], kn = knp[0];
    float invd = 1.0f / d;
    float fx = x[i], fy = y[i], fz = z[i];
    int cx = __float2int_rn(fx * invd);   // jitter |.|<=0.3 -> far from .5 boundary
    int cy = __float2int_rn(fy * invd);
    int cz = __float2int_rn(fz * invd);
    float jx = fmaf(fx, invd, -(float)cx);
    float jy = fmaf(fy, invd, -(float)cy);
    float jz = fmaf(fz, invd, -(float)cz);

    uint4 rec;
    rec.x = f2h(jx, jy);
    rec.y = f2h(jz, vx[i]);
    rec.z = f2h(vy[i], vz[i]);
    rec.w = (unsigned int)(i + 1);
    grid[(size_t)(cz * GDIM + cy) * GDIM + cx] = rec;

    // wall forces from EXACT inputs, coalesced by pid
    float two_d = 2.0f * d, ds = (float)GDIM * d;
    size_t N = (size_t)n;
    float lox = (fx != 0.0f && fx < d) ? kn * (d - fx) : 0.0f;
    float hix = (fx > ds - two_d) ? kn * (fx - ds + two_d) : 0.0f;
    float loy = (fy != 0.0f && fy < d) ? kn * (d - fy) : 0.0f;
    float hiy = (fy > ds - two_d) ? kn * (fy - ds + two_d) : 0.0f;
    float loz = (fz != 0.0f && fz < d) ? kn * (d - fz) : 0.0f;
    float hiz = (fz > ds - two_d) ? kn * (fz - ds + two_d) : 0.0f;
    out[6 * N + i] = lox - hix;
    out[7 * N + i] = loy - hiy;
    out[8 * N + i] = loz - hiz;
}

__global__ __launch_bounds__(256, 6) void force_tile_k(
    const uint4* __restrict__ grid,
    const float* __restrict__ dp, const float* __restrict__ knp,
    const float* __restrict__ etap, float* __restrict__ out, int n)
{
    __shared__ uint2 JA[HCELLS];            // jx|jy, jz|vx   13,824 B
    __shared__ unsigned int VV[HCELLS];     // vy|vz           6,912 B
    __shared__ unsigned int llist[TCELLS];  //                 2,048 B
    __shared__ int lcount;

    int tid = threadIdx.x;
    int tileid = blockIdx.x;
    int tx = tileid % NT;
    int ty = (tileid / NT) % NT;
    int tz = tileid / (NT * NT);
    int bx = tx * TILE - 2, by = ty * TILE - 2, bz = tz * TILE - 2;

    if (tid == 0) lcount = 0;
    __syncthreads();

    // ---- stage halo into LDS (folding wrap delta) + compact interior ----
    int lane = tid & 63;
    for (int h = tid; h < HCELLS; h += 256) {
        int hx = h % HALO;
        int hy = (h / HALO) % HALO;
        int hz = h / (HALO * HALO);
        int ux = bx + hx, uy = by + hy, uz = bz + hz;   // unwrapped
        int gx = ux; if (gx < 0) gx += GDIM; else if (gx >= GDIM) gx -= GDIM;
        int gy = uy; if (gy < 0) gy += GDIM; else if (gy >= GDIM) gy -= GDIM;
        int gz = uz; if (gz < 0) gz += GDIM; else if (gz >= GDIM) gz -= GDIM;
        uint4 r = grid[(size_t)(gz * GDIM + gy) * GDIM + gx];
        bool occ_any = r.w != EMPTY32;
        int Wx = gx - ux, Wy = gy - uy, Wz = gz - uz;   // 0 or +-96
        if (occ_any && ((Wx | Wy | Wz) != 0)) {
            float2 jxy = h2f(r.x), jzv = h2f(r.y);
            r.x = f2h(jxy.x + (float)Wx, jxy.y + (float)Wy);
            r.y = f2h(jzv.x + (float)Wz, jzv.y);
        }
        JA[h] = make_uint2(r.x, r.y);
        VV[h] = r.z;
        bool inter = hx >= 2 && hx < 2 + TILE && hy >= 2 && hy < 2 + TILE &&
                     hz >= 2 && hz < 2 + TILE;
        bool occ = inter && occ_any;
        unsigned long long m = __ballot(occ);
        int base = 0;
        if (lane == 0 && m) base = atomicAdd(&lcount, __popcll(m));
        base = __shfl(base, 0);
        if (occ) {
            int off = __popcll(m & ((1ull << lane) - 1ull));
            int ic = ((hz - 2) * TILE + (hy - 2)) * TILE + (hx - 2);
            llist[base + off] = (r.w << 9) | (unsigned int)ic;
        }
    }
    __syncthreads();

    float d = dp[0], kn = knp[0], eta = etap[0];
    int cnt = lcount;
    size_t N = (size_t)n;

    for (int i = tid; i < cnt; i += 256) {
        unsigned int e = llist[i];
        int lc = (int)(e & 511u);
        int pid = (int)(e >> 9) - 1;
        int lx = lc & 7, ly = (lc >> 3) & 7, lz = lc >> 6;
        int hc = ((lz + 2) * HALO + (ly + 2)) * HALO + (lx + 2);
        uint2 ja = JA[hc];
        float2 jxy = h2f(ja.x), jzw = h2f(ja.y), vyz = h2f(VV[hc]);
        float jxi = jxy.x, jyi = jxy.y, jzi = jzw.x;
        float vxi = jzw.y, vyi = vyz.x, vzi = vyz.y;

        float px[5], py[5], pz[5];
#pragma unroll
        for (int o = 0; o < 5; ++o) {
            px[o] = jxi + (float)(2 - o);
            py[o] = jyi + (float)(2 - o);
            pz[o] = jzi + (float)(2 - o);
        }

        float fxc = 0, fyc = 0, fzc = 0, fxd = 0, fyd = 0, fzd = 0;
#pragma unroll
        for (int iz = 0; iz < 5; ++iz) {
#pragma unroll
            for (int iy = 0; iy < 5; ++iy) {
                const int w = WT_[iz * 5 + iy];       // compile-time after unroll
                const int x0 = (5 - w) / 2;
                int rb = ((lz + iz) * HALO + (ly + iy)) * HALO + lx;
                float pyr = py[iy], pzr = pz[iz];
#pragma unroll
                for (int ix = x0; ix < x0 + 5; ++ix) {
                    if (ix >= x0 + w) break;          // folds after unroll
                    int idx = rb + ix;
                    uint2 j2 = JA[idx];
                    float2 njxy = h2f(j2.x), njzw = h2f(j2.y), nvyz = h2f(VV[idx]);
                    float dx = px[ix] - njxy.x;
                    float dy = pyr - njxy.y;
                    float dz = pzr - njzw.x;
                    float dvx = vxi - njzw.y;
                    float dvy = vyi - nvyz.x;
                    float dvz = vzi - nvyz.y;
                    float s = fmaf(dx, dx, fmaf(dy, dy, dz * dz));
                    float t = fmaxf(s, 4e-6f);        // = (max(eps, dist)/d)^2
                    float rinv = __builtin_amdgcn_rsqf(t);
                    float dist = s * rinv;
                    float dot = fmaf(dvx, dx, fmaf(dvy, dy, dvz * dz));
                    bool ov = dist < 2.0f;
                    float fc = ov ? (dist - 2.0f) * rinv : 0.0f;
                    float fd = ov ? dot * rinv * rinv : 0.0f;
                    fxc = fmaf(fc, dx, fxc); fyc = fmaf(fc, dy, fyc); fzc = fmaf(fc, dz, fzc);
                    fxd = fmaf(fd, dx, fxd); fyd = fmaf(fd, dy, fyd); fzd = fmaf(fd, dz, fzd);
                }
            }
        }

        // ---- empty-cell correction (reference: empty gathers read zeros ->
        // dx = p_i, contributes when |p_i| < 2d). Only origin-corner lanes.
        float pxc = (float)(tx * TILE + lx) + jxi;   // global pos, cell units
        float pyc = (float)(ty * TILE + ly) + jyi;
        float pzc = (float)(tz * TILE + lz) + jzi;
        float ss = pxc * pxc + pyc * pyc + pzc * pzc;
        if (ss < 4.0f) {
            int cntE = 0;
#pragma unroll 1
            for (int iz = 0; iz < 5; ++iz)
#pragma unroll 1
                for (int iy = 0; iy < 5; ++iy)
#pragma unroll 1
                    for (int ix = 0; ix < 5; ++ix) {
                        int hc2 = ((lz + iz) * HALO + (ly + iy)) * HALO + (lx + ix);
                        if ((JA[hc2].x & 0xFFFFu) == EMPTY16) ++cntE;
                    }
            if (cntE) {
                float t = fmaxf(ss, 4e-6f);
                float rinv = __builtin_amdgcn_rsqf(t);
                float dist = ss * rinv;
                if (dist < 2.0f) {
                    float fcE = (dist - 2.0f) * rinv;
                    float dotE = vxi * pxc + vyi * pyc + vzi * pzc;
                    float fdE = dotE * rinv * rinv;
                    float c = (float)cntE;
                    fxc = fmaf(c * fcE, pxc, fxc); fyc = fmaf(c * fcE, pyc, fyc); fzc = fmaf(c * fcE, pzc, fzc);
                    fxd = fmaf(c * fdE, pxc, fxd); fyd = fmaf(c * fdE, pyc, fyd); fzd = fmaf(c * fdE, pzc, fzd);
                }
            }
        }

        float kd = kn * d;   // cell-units -> N: spring scales by kn*d, damping by eta
        out[0 * N + pid] = fxc * kd;
        out[1 * N + pid] = fyc * kd;
        out[2 * N + pid] = fzc * kd;
        out[3 * N + pid] = fxd * eta;
        out[4 * N + pid] = fyd * eta;
        out[5 * N + pid] = fzd * eta;
    }
}

extern "C" void kernel_launch(void* const* d_in, const int* in_sizes, int n_in,
                              void* d_out, int out_size, void* d_ws, size_t ws_size,
                              hipStream_t stream)
{
    const float* x  = (const float*)d_in[0];
    const float* y  = (const float*)d_in[1];
    const float* z  = (const float*)d_in[2];
    const float* vx = (const float*)d_in[3];
    const float* vy = (const float*)d_in[4];
    const float* vz = (const float*)d_in[5];
    const float* dp   = (const float*)d_in[6];
    const float* knp  = (const float*)d_in[7];
    const float* etap = (const float*)d_in[8];
    int n = in_sizes[0];

    uint4* grid = (uint4*)d_ws;

    // 0xFB pattern: empty cells decode to huge-negative jitter (no contact),
    // pid word 0xFBFBFBFB (distinct from any pid+1 <= 400001).
    hipMemsetAsync(d_ws, 0xFB, (size_t)GCELLS * 16, stream);

    int blocks = (n + 255) / 256;
    scatter_k<<<blocks, 256, 0, stream>>>(x, y, z, vx, vy, vz, dp, knp, grid, (float*)d_out, n);
    force_tile_k<<<NT * NT * NT, 256, 0, stream>>>(grid, dp, knp, etap, (float*)d_out, n);
}

// Round 7
// 82.311 us; speedup vs baseline: 5.7670x; 5.7670x over previous
//
#include <hip/hip_runtime.h>
#include <hip/hip_fp16.h>

#define GDIM 96
#define GCELLS (GDIM * GDIM * GDIM)
#define TILE 8
#define HALO 12            // TILE + 2*2
#define NT (GDIM / TILE)   // 12 tiles per axis -> 1728 blocks
#define HCELLS (HALO * HALO * HALO)   // 1728
#define TCELLS (TILE * TILE * TILE)   // 512
#define EMPTY16 0xFBFBu
#define EMPTY32 0xFBFBFBFBu

// grid record (16 B/cell): { jx|jy<<16, jz|vx<<16, vy|vz<<16, pid+1 }
// jitter in CELL units relative to own cell center, f16. Empty cells hold the
// 0xFB memset pattern: jitter approx -6.5e4 cells -> never within contact range.
// At LDS-staging, the periodic wrap delta (0/+96/-96 cells) is folded into the
// staged jitter so wrapped neighbors sit at their true unwrapped relative
// distance (~94 cells -> no contact), matching the reference's physics.

// per-(iz,iy) x-width of offsets where a REAL neighbor can produce contact
// (dist < 2 cells given per-axis jitter <= 0.30013 cells incl. f16 rounding);
// pruned offsets have min dist >= 2.019 cells. 93 of 125 survive.
constexpr int WT_[25] = {1,3,5,3,1, 3,5,5,5,3, 5,5,5,5,5, 3,5,5,5,3, 1,3,5,3,1};

__device__ inline float2 h2f(unsigned int u) {
    union { unsigned int u; __half2 h; } c; c.u = u;
    return __half22float2(c.h);
}
__device__ inline unsigned int f2h(float a, float b) {
    union { __half2 h; unsigned int u; } c; c.h = __floats2half2_rn(a, b);
    return c.u;
}

__global__ __launch_bounds__(256) void scatter_k(
    const float* __restrict__ x, const float* __restrict__ y, const float* __restrict__ z,
    const float* __restrict__ vx, const float* __restrict__ vy, const float* __restrict__ vz,
    const float* __restrict__ dp, const float* __restrict__ knp,
    uint4* __restrict__ grid, float* __restrict__ out, int n)
{
    int i = blockIdx.x * blockDim.x + threadIdx.x;
    if (i >= n) return;
    float d = dp[0], kn = knp[0];
    float invd = 1.0f / d;
    float fx = x[i], fy = y[i], fz = z[i];
    int cx = __float2int_rn(fx * invd);   // jitter |.|<=0.3 -> far from .5 boundary
    int cy = __float2int_rn(fy * invd);
    int cz = __float2int_rn(fz * invd);
    float jx = fmaf(fx, invd, -(float)cx);
    float jy = fmaf(fy, invd, -(float)cy);
    float jz = fmaf(fz, invd, -(float)cz);

    uint4 rec;
    rec.x = f2h(jx, jy);
    rec.y = f2h(jz, vx[i]);
    rec.z = f2h(vy[i], vz[i]);
    rec.w = (unsigned int)(i + 1);
    grid[(size_t)(cz * GDIM + cy) * GDIM + cx] = rec;

    // wall forces from EXACT inputs, coalesced by pid
    float two_d = 2.0f * d, ds = (float)GDIM * d;
    size_t N = (size_t)n;
    float lox = (fx != 0.0f && fx < d) ? kn * (d - fx) : 0.0f;
    float hix = (fx > ds - two_d) ? kn * (fx - ds + two_d) : 0.0f;
    float loy = (fy != 0.0f && fy < d) ? kn * (d - fy) : 0.0f;
    float hiy = (fy > ds - two_d) ? kn * (fy - ds + two_d) : 0.0f;
    float loz = (fz != 0.0f && fz < d) ? kn * (d - fz) : 0.0f;
    float hiz = (fz > ds - two_d) ? kn * (fz - ds + two_d) : 0.0f;
    out[6 * N + i] = lox - hix;
    out[7 * N + i] = loy - hiy;
    out[8 * N + i] = loz - hiz;
}

__global__ __launch_bounds__(256, 6) void force_tile_k(
    const uint4* __restrict__ grid,
    const float* __restrict__ dp, const float* __restrict__ knp,
    const float* __restrict__ etap, float* __restrict__ out, int n)
{
    __shared__ uint2 JA[HCELLS];            // jx|jy, jz|vx   13,824 B
    __shared__ unsigned int VV[HCELLS];     // vy|vz           6,912 B
    __shared__ unsigned int llist[TCELLS];  //                 2,048 B
    __shared__ int lcount;

    int tid = threadIdx.x;
    int tileid = blockIdx.x;
    int tx = tileid % NT;
    int ty = (tileid / NT) % NT;
    int tz = tileid / (NT * NT);
    int bx = tx * TILE - 2, by = ty * TILE - 2, bz = tz * TILE - 2;

    if (tid == 0) lcount = 0;
    __syncthreads();

    // ---- stage halo into LDS (folding wrap delta) + compact interior ----
    int lane = tid & 63;
    for (int h = tid; h < HCELLS; h += 256) {
        int hx = h % HALO;
        int hy = (h / HALO) % HALO;
        int hz = h / (HALO * HALO);
        int ux = bx + hx, uy = by + hy, uz = bz + hz;   // unwrapped
        int gx = ux; if (gx < 0) gx += GDIM; else if (gx >= GDIM) gx -= GDIM;
        int gy = uy; if (gy < 0) gy += GDIM; else if (gy >= GDIM) gy -= GDIM;
        int gz = uz; if (gz < 0) gz += GDIM; else if (gz >= GDIM) gz -= GDIM;
        uint4 r = grid[(size_t)(gz * GDIM + gy) * GDIM + gx];
        bool occ_any = r.w != EMPTY32;
        int Wx = gx - ux, Wy = gy - uy, Wz = gz - uz;   // 0 or +-96
        if (occ_any && ((Wx | Wy | Wz) != 0)) {
            float2 jxy = h2f(r.x), jzv = h2f(r.y);
            r.x = f2h(jxy.x + (float)Wx, jxy.y + (float)Wy);
            r.y = f2h(jzv.x + (float)Wz, jzv.y);
        }
        JA[h] = make_uint2(r.x, r.y);
        VV[h] = r.z;
        bool inter = hx >= 2 && hx < 2 + TILE && hy >= 2 && hy < 2 + TILE &&
                     hz >= 2 && hz < 2 + TILE;
        bool occ = inter && occ_any;
        unsigned long long m = __ballot(occ);
        int base = 0;
        if (lane == 0 && m) base = atomicAdd(&lcount, __popcll(m));
        base = __shfl(base, 0);
        if (occ) {
            int off = __popcll(m & ((1ull << lane) - 1ull));
            int ic = ((hz - 2) * TILE + (hy - 2)) * TILE + (hx - 2);
            llist[base + off] = (r.w << 9) | (unsigned int)ic;
        }
    }
    __syncthreads();

    float d = dp[0], kn = knp[0], eta = etap[0];
    int cnt = lcount;
    size_t N = (size_t)n;

    for (int i = tid; i < cnt; i += 256) {
        unsigned int e = llist[i];
        int lc = (int)(e & 511u);
        int pid = (int)(e >> 9) - 1;
        int lx = lc & 7, ly = (lc >> 3) & 7, lz = lc >> 6;
        int hc = ((lz + 2) * HALO + (ly + 2)) * HALO + (lx + 2);
        uint2 ja = JA[hc];
        float2 jxy = h2f(ja.x), jzw = h2f(ja.y), vyz = h2f(VV[hc]);
        float jxi = jxy.x, jyi = jxy.y, jzi = jzw.x;
        float vxi = jzw.y, vyi = vyz.x, vzi = vyz.y;

        float fxc = 0, fyc = 0, fzc = 0, fxd = 0, fyd = 0, fzd = 0;
        // NO per-thread indexed arrays here: every loop has a compile-time
        // trip count and every offset folds to a literal (scratch-spill-safe).
#pragma unroll
        for (int iz = 0; iz < 5; ++iz) {
#pragma unroll
            for (int iy = 0; iy < 5; ++iy) {
                const int w = WT_[iz * 5 + iy];       // compile-time after unroll
                const int x0 = (5 - w) / 2;
                int rb = ((lz + iz) * HALO + (ly + iy)) * HALO + lx;
#pragma unroll
                for (int k = 0; k < w; ++k) {
                    const int ix = x0 + k;            // compile-time
                    int idx = rb + ix;
                    uint2 j2 = JA[idx];
                    float2 njxy = h2f(j2.x), njzw = h2f(j2.y), nvyz = h2f(VV[idx]);
                    float dx = (jxi - njxy.x) + (float)(2 - ix);
                    float dy = (jyi - njxy.y) + (float)(2 - iy);
                    float dz = (jzi - njzw.x) + (float)(2 - iz);
                    float dvx = vxi - njzw.y;
                    float dvy = vyi - nvyz.x;
                    float dvz = vzi - nvyz.y;
                    float s = fmaf(dx, dx, fmaf(dy, dy, dz * dz));
                    float t = fmaxf(s, 4e-6f);        // = (max(eps, dist)/d)^2
                    float rinv = __builtin_amdgcn_rsqf(t);
                    float dist = s * rinv;
                    float dot = fmaf(dvx, dx, fmaf(dvy, dy, dvz * dz));
                    bool ov = dist < 2.0f;
                    float fc = ov ? (dist - 2.0f) * rinv : 0.0f;
                    float fd = ov ? dot * rinv * rinv : 0.0f;
                    fxc = fmaf(fc, dx, fxc); fyc = fmaf(fc, dy, fyc); fzc = fmaf(fc, dz, fzc);
                    fxd = fmaf(fd, dx, fxd); fyd = fmaf(fd, dy, fyd); fzd = fmaf(fd, dz, fzd);
                }
            }
        }

        // ---- empty-cell correction (reference: empty gathers read zeros ->
        // dx = p_i, contributes when |p_i| < 2d). Only origin-corner lanes.
        float pxc = (float)(tx * TILE + lx) + jxi;   // global pos, cell units
        float pyc = (float)(ty * TILE + ly) + jyi;
        float pzc = (float)(tz * TILE + lz) + jzi;
        float ss = pxc * pxc + pyc * pyc + pzc * pzc;
        if (ss < 4.0f) {
            int cntE = 0;
#pragma unroll 1
            for (int iz = 0; iz < 5; ++iz)
#pragma unroll 1
                for (int iy = 0; iy < 5; ++iy)
#pragma unroll 1
                    for (int ix = 0; ix < 5; ++ix) {
                        int hc2 = ((lz + iz) * HALO + (ly + iy)) * HALO + (lx + ix);
                        if ((JA[hc2].x & 0xFFFFu) == EMPTY16) ++cntE;
                    }
            if (cntE) {
                float t = fmaxf(ss, 4e-6f);
                float rinv = __builtin_amdgcn_rsqf(t);
                float dist = ss * rinv;
                if (dist < 2.0f) {
                    float fcE = (dist - 2.0f) * rinv;
                    float dotE = vxi * pxc + vyi * pyc + vzi * pzc;
                    float fdE = dotE * rinv * rinv;
                    float c = (float)cntE;
                    fxc = fmaf(c * fcE, pxc, fxc); fyc = fmaf(c * fcE, pyc, fyc); fzc = fmaf(c * fcE, pzc, fzc);
                    fxd = fmaf(c * fdE, pxc, fxd); fyd = fmaf(c * fdE, pyc, fyd); fzd = fmaf(c * fdE, pzc, fzd);
                }
            }
        }

        float kd = kn * d;   // cell-units -> N: spring scales by kn*d, damping by eta
        out[0 * N + pid] = fxc * kd;
        out[1 * N + pid] = fyc * kd;
        out[2 * N + pid] = fzc * kd;
        out[3 * N + pid] = fxd * eta;
        out[4 * N + pid] = fyd * eta;
        out[5 * N + pid] = fzd * eta;
    }
}

extern "C" void kernel_launch(void* const* d_in, const int* in_sizes, int n_in,
                              void* d_out, int out_size, void* d_ws, size_t ws_size,
                              hipStream_t stream)
{
    const float* x  = (const float*)d_in[0];
    const float* y  = (const float*)d_in[1];
    const float* z  = (const float*)d_in[2];
    const float* vx = (const float*)d_in[3];
    const float* vy = (const float*)d_in[4];
    const float* vz = (const float*)d_in[5];
    const float* dp   = (const float*)d_in[6];
    const float* knp  = (const float*)d_in[7];
    const float* etap = (const float*)d_in[8];
    int n = in_sizes[0];

    uint4* grid = (uint4*)d_ws;

    // 0xFB pattern: empty cells decode to huge-negative jitter (no contact),
    // pid word 0xFBFBFBFB (distinct from any pid+1 <= 400001).
    hipMemsetAsync(d_ws, 0xFB, (size_t)GCELLS * 16, stream);

    int blocks = (n + 255) / 256;
    scatter_k<<<blocks, 256, 0, stream>>>(x, y, z, vx, vy, vz, dp, knp, grid, (float*)d_out, n);
    force_tile_k<<<NT * NT * NT, 256, 0, stream>>>(grid, dp, knp, etap, (float*)d_out, n);
}